// Round 1
// 5314.199 us; speedup vs baseline: 1.0077x; 1.0077x over previous
//
#include <hip/hip_runtime.h>
#include <stdint.h>

#define N_SITES 131072
#define CIN0 256
#define HID 512
#define KTAPS 9
#define NLAYERS 8

typedef __bf16 bf16x8 __attribute__((ext_vector_type(8)));
typedef float f32x4 __attribute__((ext_vector_type(4)));

__device__ __forceinline__ unsigned short f2bf(float f) {
    union { float f; unsigned u; } v; v.f = f;
    return (unsigned short)((v.u + 0x7fffu + ((v.u >> 16) & 1u)) >> 16);
}

// ---------------- prep kernels ----------------

__global__ void cvt_features_kernel(const float* __restrict__ in, unsigned short* __restrict__ out) {
    int t = blockIdx.x * 256 + threadIdx.x;
    const float4* p = (const float4*)in + 2 * (size_t)t;
    float4 a = p[0], b = p[1];
    uint4 o;
    o.x = f2bf(a.x) | ((unsigned)f2bf(a.y) << 16);
    o.y = f2bf(a.z) | ((unsigned)f2bf(a.w) << 16);
    o.z = f2bf(b.x) | ((unsigned)f2bf(b.y) << 16);
    o.w = f2bf(b.z) | ((unsigned)f2bf(b.w) << 16);
    ((uint4*)out)[t] = o;
}

// Seed the zero-gather rows (row N_SITES) in BOTH ping-pong buffers.
// xF: ws buffer (512-wide layout). xO: d_out-aliased buffer (256-wide layout
// for layer-0 features AND 512-wide layout for odd-layer outputs).
// GEMM epilogues only ever write rows < N_SITES, so these stay zero.
__global__ void zero_rows_kernel(unsigned short* __restrict__ xf, unsigned short* __restrict__ xo) {
    int t = threadIdx.x; // 256 threads
    xf[(size_t)N_SITES * 512 + t] = 0;
    xf[(size_t)N_SITES * 512 + 256 + t] = 0;
    xo[(size_t)N_SITES * 256 + t] = 0;
    xo[(size_t)N_SITES * 512 + t] = 0;
    xo[(size_t)N_SITES * 512 + 256 + t] = 0;
}

// w fp32 [T][cin][512] -> bf16 [T][512][cin]
__global__ void transpose_w_kernel(const float* __restrict__ in, unsigned short* __restrict__ out, int cin) {
    __shared__ float tile[32][33];
    int m = blockIdx.z;
    int nb = blockIdx.x * 32;
    int cb = blockIdx.y * 32;
    int tx = threadIdx.x, ty = threadIdx.y;
    const float* src = in + (size_t)m * cin * HID;
    unsigned short* dst = out + (size_t)m * HID * cin;
#pragma unroll
    for (int j = 0; j < 4; ++j) {
        int r = ty + 8 * j;
        tile[r][tx] = src[(size_t)(cb + r) * HID + nb + tx];
    }
    __syncthreads();
#pragma unroll
    for (int j = 0; j < 4; ++j) {
        int r = ty + 8 * j;
        dst[(size_t)(nb + r) * cin + cb + tx] = f2bf(tile[tx][r]);
    }
}

// ---------------- gathered GEMM + fused GroupNorm/ReLU ----------------

__device__ __forceinline__ void async16(const void* g, void* l) {
    __builtin_amdgcn_global_load_lds(
        (__attribute__((address_space(1))) unsigned int*)(g),
        (__attribute__((address_space(3))) unsigned int*)(l),
        16, 0, 0);
}

// out[rowbase+m][colbase+n] = GN+ReLU( sum_tap sum_k x[nbr[m,tap]][k] * wt[tap][n][k] )
// GN group = 16 contiguous channels = exactly one 16-wide MFMA fragment, so
// group stats reduce across lane&15 (the col axis of the C/D fragment).
__global__ __launch_bounds__(256, 4) void subm_gemm_gn_kernel(
    const unsigned short* __restrict__ x,
    const int* __restrict__ nbr,
    const unsigned short* __restrict__ wt,
    const float* __restrict__ gamma,
    const float* __restrict__ beta,
    void* __restrict__ obuf,
    int cin, int write_bf16)
{
    __shared__ uint4 As[1024];
    __shared__ uint4 Bs[1024];

    const int tid = threadIdx.x;
    const int lane = tid & 63;
    const int wave = tid >> 6;

    // XCD/L2-aware swizzle. Dispatch round-robins blocks across 8 XCDs
    // (xcd = blockIdx % 8). Give each XCD a FIXED col-tile (B slice 1.18 MB
    // stays L2-resident) and a CONTIGUOUS rb sweep (gather windows of
    // consecutive rb overlap ~89% -> A tiles hit L2, not L3/HBM).
    const int b = (int)blockIdx.x;
    const int xcd = b & 7;
    const int slot = b >> 3;                  // 0..511
    const int colbase = (xcd & 3) * 128;
    const int rowbase = ((xcd >> 2) * 512 + slot) * 128;

    const int wm = (wave >> 1) * 64;
    const int wn = (wave & 1) * 64;

    const int r0 = tid >> 3;                  // 0..31
    const int cs = tid & 7;
    const int chunk = cs ^ (r0 & 7);
    const int ldsbase = tid & ~63;
    const int kiters = cin >> 6;

    const f32x4 zero4 = {0.f, 0.f, 0.f, 0.f};
    f32x4 acc[4][4];
#pragma unroll
    for (int i = 0; i < 4; ++i)
#pragma unroll
        for (int j = 0; j < 4; ++j)
            acc[i][j] = zero4;

    for (int tap = 0; tap < KTAPS; ++tap) {
        const unsigned short* arow[4];
#pragma unroll
        for (int i = 0; i < 4; ++i) {
            int idx = nbr[(size_t)(rowbase + r0 + 32 * i) * KTAPS + tap];
            if (idx < 0) idx = N_SITES;
            arow[i] = x + (size_t)idx * cin + chunk * 8;
        }
        const unsigned short* wbase = wt + ((size_t)tap * HID + colbase) * cin + chunk * 8;
        const unsigned short* brow[4];
#pragma unroll
        for (int i = 0; i < 4; ++i)
            brow[i] = wbase + (size_t)(r0 + 32 * i) * cin;

        for (int kk = 0; kk < kiters; ++kk) {
            const int ko = kk * 64;
            __syncthreads();
#pragma unroll
            for (int i = 0; i < 4; ++i) {
                async16(arow[i] + ko, &As[ldsbase + 256 * i]);
                async16(brow[i] + ko, &Bs[ldsbase + 256 * i]);
            }
            __syncthreads();

#pragma unroll
            for (int ks = 0; ks < 2; ++ks) {
                bf16x8 af[4], bfr[4];
#pragma unroll
                for (int f = 0; f < 4; ++f) {
                    int rl = wm + f * 16 + (lane & 15);
                    int ch = ks * 4 + (lane >> 4);
                    af[f]  = __builtin_bit_cast(bf16x8, As[rl * 8 + (ch ^ (rl & 7))]);
                    int cl = wn + f * 16 + (lane & 15);
                    bfr[f] = __builtin_bit_cast(bf16x8, Bs[cl * 8 + (ch ^ (cl & 7))]);
                }
#pragma unroll
                for (int i = 0; i < 4; ++i)
#pragma unroll
                    for (int j = 0; j < 4; ++j)
                        acc[i][j] = __builtin_amdgcn_mfma_f32_16x16x32_bf16(af[i], bfr[j], acc[i][j], 0, 0, 0);
            }
        }
    }

    // ---- fused GroupNorm + ReLU epilogue ----
    // C/D fragment: col = lane&15, row = (lane>>4)*4 + reg.
    // Each j-fragment's 16 cols are one full GN group -> butterfly over lane bits 0..3.
    float gv[4], bv[4];
#pragma unroll
    for (int j = 0; j < 4; ++j) {
        int gcol = colbase + wn + j * 16 + (lane & 15);
        gv[j] = gamma[gcol];
        bv[j] = beta[gcol];
    }

    unsigned short* bf_out = (unsigned short*)obuf;
    float* f_out = (float*)obuf;

#pragma unroll
    for (int i = 0; i < 4; ++i) {
        const int grow = rowbase + wm + i * 16 + (lane >> 4) * 4;
#pragma unroll
        for (int j = 0; j < 4; ++j) {
            const int gcol = colbase + wn + j * 16 + (lane & 15);
            f32x4 v = acc[i][j];
            f32x4 s = v;
            f32x4 q = v * v;
#pragma unroll
            for (int m = 1; m < 16; m <<= 1) {
#pragma unroll
                for (int r = 0; r < 4; ++r) {
                    s[r] += __shfl_xor(s[r], m);
                    q[r] += __shfl_xor(q[r], m);
                }
            }
            f32x4 y;
#pragma unroll
            for (int r = 0; r < 4; ++r) {
                float mu = s[r] * 0.0625f;
                float rstd = rsqrtf(q[r] * 0.0625f - mu * mu + 1e-5f);
                y[r] = fmaxf(0.f, (v[r] - mu) * rstd * gv[j] + bv[j]);
            }
            if (write_bf16) {
#pragma unroll
                for (int r = 0; r < 4; ++r)
                    bf_out[(size_t)(grow + r) * HID + gcol] = f2bf(y[r]);
            } else {
#pragma unroll
                for (int r = 0; r < 4; ++r)
                    f_out[(size_t)(grow + r) * HID + gcol] = y[r];
            }
        }
    }
}

// ---------------- launch ----------------

extern "C" void kernel_launch(void* const* d_in, const int* in_sizes, int n_in,
                              void* d_out, int out_size, void* d_ws, size_t ws_size,
                              hipStream_t stream) {
    const float* features = (const float*)d_in[0];
    const int*   nbr      = (const int*)d_in[1];
    const float* w0       = (const float*)d_in[2];
    const float* w_rest   = (const float*)d_in[3];
    const float* gamma    = (const float*)d_in[4];
    const float* beta     = (const float*)d_in[5];

    // Ping-pong bf16 activation buffers:
    //   F = workspace buffer; O = alias of d_out (dead as f32 until last layer).
    // Chain: cvt->O, L0: O->F, L1: F->O, ..., L6: O->F, L7: F->d_out(f32).
    // Last layer's input (F) never aliases d_out, so the f32 write is safe.
    unsigned short* xF = (unsigned short*)d_ws;
    size_t xbytes = (size_t)(N_SITES + 1) * HID * sizeof(unsigned short);
    unsigned short* w0t = (unsigned short*)((char*)d_ws + xbytes);
    size_t w0t_bytes = (size_t)KTAPS * HID * CIN0 * sizeof(unsigned short);
    unsigned short* wrt = (unsigned short*)((char*)d_ws + xbytes + w0t_bytes);
    unsigned short* xO = (unsigned short*)d_out;

    cvt_features_kernel<<<N_SITES * CIN0 / (256 * 8), 256, 0, stream>>>(features, xO);
    zero_rows_kernel<<<1, 256, 0, stream>>>(xF, xO);
    transpose_w_kernel<<<dim3(HID / 32, CIN0 / 32, KTAPS), dim3(32, 8), 0, stream>>>(w0, w0t, CIN0);
    transpose_w_kernel<<<dim3(HID / 32, HID / 32, (NLAYERS - 1) * KTAPS), dim3(32, 8), 0, stream>>>(w_rest, wrt, HID);

    for (int l = 0; l < NLAYERS; ++l) {
        const unsigned short* wt = (l == 0) ? w0t : wrt + (size_t)(l - 1) * KTAPS * HID * HID;
        int cin = (l == 0) ? CIN0 : HID;
        const unsigned short* xin = (l & 1) ? xF : xO;   // L0 reads O (features)
        void* obuf = (l == NLAYERS - 1) ? d_out : (void*)((l & 1) ? xO : xF);
        subm_gemm_gn_kernel<<<(N_SITES / 128) * 4, 256, 0, stream>>>(
            xin, nbr, wt, gamma + (size_t)l * HID, beta + (size_t)l * HID,
            obuf, cin, (l < NLAYERS - 1) ? 1 : 0);
    }
}

// Round 2
// 4820.589 us; speedup vs baseline: 1.1109x; 1.1024x over previous
//
#include <hip/hip_runtime.h>
#include <stdint.h>

#define N_SITES 131072
#define CIN0 256
#define HID 512
#define KTAPS 9
#define NLAYERS 8

typedef __bf16 bf16x8 __attribute__((ext_vector_type(8)));
typedef float f32x4 __attribute__((ext_vector_type(4)));

__device__ __forceinline__ unsigned short f2bf(float f) {
    union { float f; unsigned u; } v; v.f = f;
    return (unsigned short)((v.u + 0x7fffu + ((v.u >> 16) & 1u)) >> 16);
}

// ---------------- prep kernels ----------------

__global__ void cvt_features_kernel(const float* __restrict__ in, unsigned short* __restrict__ out) {
    int t = blockIdx.x * 256 + threadIdx.x;
    const float4* p = (const float4*)in + 2 * (size_t)t;
    float4 a = p[0], b = p[1];
    uint4 o;
    o.x = f2bf(a.x) | ((unsigned)f2bf(a.y) << 16);
    o.y = f2bf(a.z) | ((unsigned)f2bf(a.w) << 16);
    o.z = f2bf(b.x) | ((unsigned)f2bf(b.y) << 16);
    o.w = f2bf(b.z) | ((unsigned)f2bf(b.w) << 16);
    ((uint4*)out)[t] = o;
}

// Seed the zero-gather rows (row N_SITES) in BOTH ping-pong buffers.
// GEMM epilogues only ever write rows < N_SITES, so these stay zero.
__global__ void zero_rows_kernel(unsigned short* __restrict__ xf, unsigned short* __restrict__ xo) {
    int t = threadIdx.x; // 256 threads
    xf[(size_t)N_SITES * 512 + t] = 0;
    xf[(size_t)N_SITES * 512 + 256 + t] = 0;
    xo[(size_t)N_SITES * 256 + t] = 0;
    xo[(size_t)N_SITES * 512 + t] = 0;
    xo[(size_t)N_SITES * 512 + 256 + t] = 0;
}

// w fp32 [T][cin][512] -> bf16 [T][512][cin]
__global__ void transpose_w_kernel(const float* __restrict__ in, unsigned short* __restrict__ out, int cin) {
    __shared__ float tile[32][33];
    int m = blockIdx.z;
    int nb = blockIdx.x * 32;
    int cb = blockIdx.y * 32;
    int tx = threadIdx.x, ty = threadIdx.y;
    const float* src = in + (size_t)m * cin * HID;
    unsigned short* dst = out + (size_t)m * HID * cin;
#pragma unroll
    for (int j = 0; j < 4; ++j) {
        int r = ty + 8 * j;
        tile[r][tx] = src[(size_t)(cb + r) * HID + nb + tx];
    }
    __syncthreads();
#pragma unroll
    for (int j = 0; j < 4; ++j) {
        int r = ty + 8 * j;
        dst[(size_t)(nb + r) * cin + cb + tx] = f2bf(tile[tx][r]);
    }
}

// ---------------- gathered GEMM + fused GroupNorm/ReLU ----------------

__device__ __forceinline__ void async16(const void* g, void* l) {
    __builtin_amdgcn_global_load_lds(
        (__attribute__((address_space(1))) unsigned int*)(g),
        (__attribute__((address_space(3))) unsigned int*)(l),
        16, 0, 0);
}

// out[rowbase+m][colbase+n] = GN+ReLU( sum_tap sum_k x[nbr[m,tap]][k] * wt[tap][n][k] )
__global__ __launch_bounds__(256, 4) void subm_gemm_gn_kernel(
    const unsigned short* __restrict__ x,
    const int* __restrict__ nbr,
    const unsigned short* __restrict__ wt,
    const float* __restrict__ gamma,
    const float* __restrict__ beta,
    void* __restrict__ obuf,
    int cin, int write_bf16)
{
    __shared__ uint4 smem[2048];     // 32 KB: As | Bs in main loop, f32 half-tile in epilogue
    uint4* const As = smem;
    uint4* const Bs = smem + 1024;

    const int tid = threadIdx.x;
    const int lane = tid & 63;
    const int wave = tid >> 6;

    // XCD/L2-aware swizzle. Each XCD gets a FIXED col-tile (B slice stays
    // L2-resident) and a CONTIGUOUS rb sweep (gather windows overlap in L2).
    const int b = (int)blockIdx.x;
    const int xcd = b & 7;
    const int slot = b >> 3;                  // 0..511
    const int colbase = (xcd & 3) * 128;
    const int rowbase = ((xcd >> 2) * 512 + slot) * 128;

    const int wm = (wave >> 1) * 64;
    const int wn = (wave & 1) * 64;

    const int r0 = tid >> 3;                  // 0..31
    const int cs = tid & 7;
    const int chunk = cs ^ (r0 & 7);
    const int ldsbase = tid & ~63;
    const int kiters = cin >> 6;

    const f32x4 zero4 = {0.f, 0.f, 0.f, 0.f};
    f32x4 acc[4][4];
#pragma unroll
    for (int i = 0; i < 4; ++i)
#pragma unroll
        for (int j = 0; j < 4; ++j)
            acc[i][j] = zero4;

    for (int tap = 0; tap < KTAPS; ++tap) {
        const unsigned short* arow[4];
#pragma unroll
        for (int i = 0; i < 4; ++i) {
            int idx = nbr[(size_t)(rowbase + r0 + 32 * i) * KTAPS + tap];
            if (idx < 0) idx = N_SITES;
            arow[i] = x + (size_t)idx * cin + chunk * 8;
        }
        const unsigned short* wbase = wt + ((size_t)tap * HID + colbase) * cin + chunk * 8;
        const unsigned short* brow[4];
#pragma unroll
        for (int i = 0; i < 4; ++i)
            brow[i] = wbase + (size_t)(r0 + 32 * i) * cin;

        for (int kk = 0; kk < kiters; ++kk) {
            const int ko = kk * 64;
            __syncthreads();
#pragma unroll
            for (int i = 0; i < 4; ++i) {
                async16(arow[i] + ko, &As[ldsbase + 256 * i]);
                async16(brow[i] + ko, &Bs[ldsbase + 256 * i]);
            }
            __syncthreads();

#pragma unroll
            for (int ks = 0; ks < 2; ++ks) {
                bf16x8 af[4], bfr[4];
#pragma unroll
                for (int f = 0; f < 4; ++f) {
                    int rl = wm + f * 16 + (lane & 15);
                    int ch = ks * 4 + (lane >> 4);
                    af[f]  = __builtin_bit_cast(bf16x8, As[rl * 8 + (ch ^ (rl & 7))]);
                    int cl = wn + f * 16 + (lane & 15);
                    bfr[f] = __builtin_bit_cast(bf16x8, Bs[cl * 8 + (ch ^ (cl & 7))]);
                }
#pragma unroll
                for (int i = 0; i < 4; ++i)
#pragma unroll
                    for (int j = 0; j < 4; ++j)
                        acc[i][j] = __builtin_amdgcn_mfma_f32_16x16x32_bf16(af[i], bfr[j], acc[i][j], 0, 0, 0);
            }
        }
    }

    // ---- fused GroupNorm + ReLU epilogue (LDS-transpose, two half-tile passes) ----
    // Pass p stages fragments i = 2p,2p+1 from ALL waves (64 tile-rows) into
    // 32 KB LDS as f32 [col][64] with XOR bank swizzle, then 256 threads each
    // own 4 rows x 8 cols: group stats = in-lane accumulate + ONE partner
    // shuffle (group = 16 cols = 2 threads). Stores are 16B-contiguous.
    float* E = (float*)smem;          // 8192 floats
    const int m4 = tid & 15;          // col segment (8 cols)
    const int qv = tid >> 4;          // row quad (local rows qv*4..+3)
    const int c0 = m4 * 8;

    unsigned short* bf_out = (unsigned short*)obuf;
    float* f_out = (float*)obuf;

#pragma unroll
    for (int pass = 0; pass < 2; ++pass) {
        __syncthreads();
#pragma unroll
        for (int ii = 0; ii < 2; ++ii) {
            const int lrow = (wave >> 1) * 32 + ii * 16 + (lane >> 4) * 4; // 0..60
#pragma unroll
            for (int j = 0; j < 4; ++j) {
                const int col = wn + j * 16 + (lane & 15);
                const int idx = col * 64 + (lrow ^ (((col >> 3) & 7) << 2));
                *(f32x4*)&E[idx] = acc[pass * 2 + ii][j];
            }
        }
        __syncthreads();

        // stats sweep: 8 cols in-lane, combine halves of the 16-col group
        f32x4 s = zero4, qq = zero4;
#pragma unroll
        for (int cc = 0; cc < 8; ++cc) {
            const int col = c0 + cc;
            const f32x4 v = *(const f32x4*)&E[col * 64 + ((qv * 4) ^ (((col >> 3) & 7) << 2))];
            s += v;
            qq += v * v;
        }
        f32x4 mu, rstd;
#pragma unroll
        for (int r = 0; r < 4; ++r) {
            s[r] += __shfl_xor(s[r], 1);
            qq[r] += __shfl_xor(qq[r], 1);
            mu[r] = s[r] * 0.0625f;
            rstd[r] = rsqrtf(qq[r] * 0.0625f - mu[r] * mu[r] + 1e-5f);
        }

        if (write_bf16) {
            unsigned pk[4][4];
#pragma unroll
            for (int cc = 0; cc < 8; ++cc) {
                const int col = c0 + cc;
                const f32x4 v = *(const f32x4*)&E[col * 64 + ((qv * 4) ^ (((col >> 3) & 7) << 2))];
                const float g = gamma[colbase + col];
                const float bt = beta[colbase + col];
#pragma unroll
                for (int r = 0; r < 4; ++r) {
                    float y = fmaxf(0.f, (v[r] - mu[r]) * rstd[r] * g + bt);
                    unsigned short h = f2bf(y);
                    if (cc & 1) pk[r][cc >> 1] |= ((unsigned)h << 16);
                    else        pk[r][cc >> 1] = h;
                }
            }
#pragma unroll
            for (int r = 0; r < 4; ++r) {
                const int l = qv * 4 + r;
                const int grow = rowbase + (l & 31) + ((l >> 5) << 6) + pass * 32;
                uint4 o; o.x = pk[r][0]; o.y = pk[r][1]; o.z = pk[r][2]; o.w = pk[r][3];
                *(uint4*)&bf_out[(size_t)grow * HID + colbase + c0] = o;
            }
        } else {
#pragma unroll
            for (int r = 0; r < 4; ++r) {
                const int l = qv * 4 + r;
                const int grow = rowbase + (l & 31) + ((l >> 5) << 6) + pass * 32;
                float* dst = f_out + (size_t)grow * HID + colbase + c0;
#pragma unroll
                for (int ccq = 0; ccq < 2; ++ccq) {
                    f32x4 y4;
#pragma unroll
                    for (int k = 0; k < 4; ++k) {
                        const int col = c0 + ccq * 4 + k;
                        const float vv = E[col * 64 + ((qv * 4) ^ (((col >> 3) & 7) << 2)) + r];
                        y4[k] = fmaxf(0.f, (vv - mu[r]) * rstd[r] * gamma[colbase + col] + beta[colbase + col]);
                    }
                    *(f32x4*)(dst + ccq * 4) = y4;
                }
            }
        }
    }
}

// ---------------- launch ----------------

extern "C" void kernel_launch(void* const* d_in, const int* in_sizes, int n_in,
                              void* d_out, int out_size, void* d_ws, size_t ws_size,
                              hipStream_t stream) {
    const float* features = (const float*)d_in[0];
    const int*   nbr      = (const int*)d_in[1];
    const float* w0       = (const float*)d_in[2];
    const float* w_rest   = (const float*)d_in[3];
    const float* gamma    = (const float*)d_in[4];
    const float* beta     = (const float*)d_in[5];

    // Ping-pong bf16 activation buffers:
    //   F = workspace buffer; O = alias of d_out (dead as f32 until last layer).
    // Chain: cvt->O, L0: O->F, L1: F->O, ..., L6: O->F, L7: F->d_out(f32).
    unsigned short* xF = (unsigned short*)d_ws;
    size_t xbytes = (size_t)(N_SITES + 1) * HID * sizeof(unsigned short);
    unsigned short* w0t = (unsigned short*)((char*)d_ws + xbytes);
    size_t w0t_bytes = (size_t)KTAPS * HID * CIN0 * sizeof(unsigned short);
    unsigned short* wrt = (unsigned short*)((char*)d_ws + xbytes + w0t_bytes);
    unsigned short* xO = (unsigned short*)d_out;

    cvt_features_kernel<<<N_SITES * CIN0 / (256 * 8), 256, 0, stream>>>(features, xO);
    zero_rows_kernel<<<1, 256, 0, stream>>>(xF, xO);
    transpose_w_kernel<<<dim3(HID / 32, CIN0 / 32, KTAPS), dim3(32, 8), 0, stream>>>(w0, w0t, CIN0);
    transpose_w_kernel<<<dim3(HID / 32, HID / 32, (NLAYERS - 1) * KTAPS), dim3(32, 8), 0, stream>>>(w_rest, wrt, HID);

    for (int l = 0; l < NLAYERS; ++l) {
        const unsigned short* wt = (l == 0) ? w0t : wrt + (size_t)(l - 1) * KTAPS * HID * HID;
        int cin = (l == 0) ? CIN0 : HID;
        const unsigned short* xin = (l & 1) ? xF : xO;   // L0 reads O (features)
        void* obuf = (l == NLAYERS - 1) ? d_out : (void*)((l & 1) ? xO : xF);
        subm_gemm_gn_kernel<<<(N_SITES / 128) * 4, 256, 0, stream>>>(
            xin, nbr, wt, gamma + (size_t)l * HID, beta + (size_t)l * HID,
            obuf, cin, (l < NLAYERS - 1) ? 1 : 0);
    }
}